// Round 14
// baseline (221.099 us; speedup 1.0000x reference)
//
#include <hip/hip_runtime.h>
#include <hip/hip_bf16.h>
#include <cstdint>
#include <cstddef>

#define B_ROWS 16384
#define D_DIM  256
#define TEMP_INV 14.285714285714286f   // 1/0.07

#define BM 256
#define BN 128
#define BK 128   // fp8 elems per K-tile -> 128 B LDS row stride (proven conflict-free)

using frag_cd = __attribute__((ext_vector_type(4))) float;   // 4 fp32
using i32x4   = __attribute__((ext_vector_type(4))) int;     // one 16B LDS chunk
using i32x8   = __attribute__((ext_vector_type(8))) int;     // 32B f8f6f4 operand

__device__ __forceinline__ void gld_lds16(const void* g, void* l) {
    __builtin_amdgcn_global_load_lds(
        (const __attribute__((address_space(1))) void*)g,
        (__attribute__((address_space(3))) void*)l,
        16, 0, 0);
}

// Kernel 1: L2-normalize q,d rows -> fp8 e4m3 (HW cvt_pk, RNE); diag[i] exact fp32.
// Also zero-initializes row_sums/col_sums/out (replaces memset dispatches).
__global__ __launch_bounds__(256) void norm_diag_kernel(
    const float* __restrict__ q, const float* __restrict__ d,
    unsigned int* __restrict__ qn, unsigned int* __restrict__ dn,
    float* __restrict__ diag,
    float* __restrict__ row_sums, float* __restrict__ col_sums,
    float* __restrict__ out) {
    const int b = blockIdx.x;
    if (b < 64)            row_sums[b * 256 + threadIdx.x] = 0.0f;
    else if (b < 128)      col_sums[(b - 64) * 256 + threadIdx.x] = 0.0f;
    else if (b == 128 && threadIdx.x == 0) out[0] = 0.0f;

    const int row  = b * 4 + (threadIdx.x >> 6);
    const int lane = threadIdx.x & 63;

    const float4 qv = ((const float4*)(q + (size_t)row * D_DIM))[lane];
    const float4 dv = ((const float4*)(d + (size_t)row * D_DIM))[lane];

    float qss = qv.x*qv.x + qv.y*qv.y + qv.z*qv.z + qv.w*qv.w;
    float dss = dv.x*dv.x + dv.y*dv.y + dv.z*dv.z + dv.w*dv.w;
    float qd  = qv.x*dv.x + qv.y*dv.y + qv.z*dv.z + qv.w*dv.w;
#pragma unroll
    for (int off = 32; off; off >>= 1) {
        qss += __shfl_down(qss, off);
        dss += __shfl_down(dss, off);
        qd  += __shfl_down(qd,  off);
    }
    qss = __shfl(qss, 0);
    dss = __shfl(dss, 0);
    qd  = __shfl(qd,  0);

    const float qinv = 1.0f / fmaxf(sqrtf(qss), 1e-12f);
    const float dinv = 1.0f / fmaxf(sqrtf(dss), 1e-12f);

    // Pack 4 normalized values -> 4 fp8 e4m3 bytes (OCP, HW round-nearest-even).
    int qp = 0, dp = 0;
    qp = __builtin_amdgcn_cvt_pk_fp8_f32(qv.x * qinv, qv.y * qinv, qp, false);
    qp = __builtin_amdgcn_cvt_pk_fp8_f32(qv.z * qinv, qv.w * qinv, qp, true);
    dp = __builtin_amdgcn_cvt_pk_fp8_f32(dv.x * dinv, dv.y * dinv, dp, false);
    dp = __builtin_amdgcn_cvt_pk_fp8_f32(dv.z * dinv, dv.w * dinv, dp, true);
    qn[row * (D_DIM / 4) + lane] = (unsigned int)qp;
    dn[row * (D_DIM / 4) + lane] = (unsigned int)dp;

    if (lane == 0) diag[row] = qd * qinv * dinv * TEMP_INV;
}

// Kernel 2: 256x128 tile of sim = qn . dn^T in fp8 e4m3; fused exp(sim - 1/T) sums.
// R13 inner loop unchanged (BK=128 fp8, 128B rows, 16B-chunk XOR swizzle, 2-stage
// K-loop / 3 barriers, mfma_scale 16x16x128 at unit scales, quad owns logical
// chunks {q,q+4} -> ds_read_b128 at PC=q^(l15&7) and PC^4 — measured 0 conflicts;
// union operand loads; exp2+packed-f32 epilogue; butterfly all-to-all reduce).
// R14: 8-WAVE / 512-THREAD BLOCKS on a 256x128 tile (waves 4x2, each wave keeps
// its 64x64 job). Rationale: measured gemm cycles ≈ SUM of VALU+LDS+MFMA pipe
// costs (no overlap) and occupancy pins at ~2.4 BLOCKS/CU regardless of LDS/VGPR
// — so buy wave-TLP per block. Also -25% staging bytes (B shared by 256 rows).
__global__ __launch_bounds__(512) void gemm_lse_kernel(
    const unsigned char* __restrict__ qn, const unsigned char* __restrict__ dn,
    float* __restrict__ row_sums, float* __restrict__ col_sums) {
    __shared__ unsigned char As[BM][BK];   // 32 KB
    __shared__ unsigned char Bs[BN][BK];   // 16 KB

    const int t    = threadIdx.x;
    const int lane = t & 63;
    const int w    = t >> 6;               // 0..7
    const int l15  = lane & 15;
    const int quad = lane >> 4;
    const int m0   = (w >> 1) * 64;        // 0,64,128,192
    const int n0   = (w & 1) * 64;         // 0,64

    // XCD swizzle: id -> (bx, by); grid = 128 x 64 tiles
    const int id  = blockIdx.x;
    const int xcd = id & 7;
    const int j   = id >> 3;               // 0..1023
    const int bx  = (xcd << 4) | (j & 15); // 0..127
    const int by  = j >> 4;                // 0..63
    const int rowBase = by * BM;
    const int colBase = bx * BN;

    // staging: thread t -> row t/8 (+64/issue), phys 16B chunk p=t&7,
    // GLOBAL logical chunk g = p^(row&7); LDS offset = t*16.
    const int rsub = t >> 3;               // 0..63
    const int g    = ((t & 7) ^ (rsub & 7)) << 4;   // byte offset of logical chunk
    const unsigned char* ga = qn + (size_t)(rowBase + rsub) * D_DIM + g;
    const unsigned char* gb = dn + (size_t)(colBase + rsub) * D_DIM + g;
    unsigned char* la = &As[0][0] + t * 16;
    unsigned char* lb = &Bs[0][0] + t * 16;

    frag_cd acc[4][4];
#pragma unroll
    for (int i = 0; i < 4; ++i)
#pragma unroll
        for (int jj = 0; jj < 4; ++jj)
            acc[i][jj] = (frag_cd){0.0f, 0.0f, 0.0f, 0.0f};

    // quad's two swizzled chunks (logical pair {q, q+4}): PCa and PCa^4.
    const int PCa = quad ^ (l15 & 7);

    union OpU { i32x8 v; i32x4 h[2]; };

    for (int kt = 0; kt < D_DIM; kt += BK) {
        if (kt) __syncthreads();
#pragma unroll
        for (int it = 0; it < 4; ++it)     // A: 4 issues x 64 rows (row&7 invariant)
            gld_lds16(ga + (size_t)it * 64 * D_DIM + kt, la + it * 64 * BK);
#pragma unroll
        for (int it = 0; it < 2; ++it)     // B: 2 issues x 64 rows
            gld_lds16(gb + (size_t)it * 64 * D_DIM + kt, lb + it * 64 * BK);
        __syncthreads();   // drains vmcnt (gld_lds) + orders LDS

        OpU a8[4], b8[4];
#pragma unroll
        for (int i = 0; i < 4; ++i) {
            const unsigned char* rA = &As[m0 + i * 16 + l15][0];
            a8[i].h[0] = *(const i32x4*)(rA + PCa * 16);
            a8[i].h[1] = *(const i32x4*)(rA + (PCa ^ 4) * 16);
        }
#pragma unroll
        for (int i = 0; i < 4; ++i) {
            const unsigned char* rB = &Bs[n0 + i * 16 + l15][0];
            b8[i].h[0] = *(const i32x4*)(rB + PCa * 16);
            b8[i].h[1] = *(const i32x4*)(rB + (PCa ^ 4) * 16);
        }
#pragma unroll
        for (int mi = 0; mi < 4; ++mi)
#pragma unroll
            for (int ni = 0; ni < 4; ++ni)
                acc[mi][ni] = __builtin_amdgcn_mfma_scale_f32_16x16x128_f8f6f4(
                    a8[mi].v, b8[ni].v, acc[mi][ni],
                    0, 0,                      // cbsz=FP8 e4m3, blgp=FP8 e4m3
                    0, 0x7F7F7F7F,             // opsel_a, scale_a = 1.0 per block
                    0, 0x7F7F7F7F);            // opsel_b, scale_b = 1.0 per block
    }

    // ---- Epilogue ----
    // C frag layout (shape-determined — m89/m127/m128):
    // lane holds col = n0+ni*16+l15, row = m0+mi*16+quad*4+r.
    // e = exp(sim - 1/T) = 2^(acc*C - C), C = (1/T)*log2(e). Packed float4 math.
    const float C2 = TEMP_INV * 1.44269504088896f;
    union { frag_cd v[4]; float f[16]; } rvu;
    frag_cd cv4[4];
#pragma unroll
    for (int i = 0; i < 4; ++i) {
        rvu.v[i] = (frag_cd){0.0f, 0.0f, 0.0f, 0.0f};
        cv4[i]   = (frag_cd){0.0f, 0.0f, 0.0f, 0.0f};
    }
#pragma unroll
    for (int mi = 0; mi < 4; ++mi)
#pragma unroll
        for (int ni = 0; ni < 4; ++ni) {
            const frag_cd tt = acc[mi][ni] * C2 - C2;   // v_pk_fma_f32 x2
            frag_cd e;
#pragma unroll
            for (int r = 0; r < 4; ++r) e[r] = __builtin_amdgcn_exp2f(tt[r]);
            rvu.v[mi] += e;   // row partials (sum over ni)
            cv4[ni]   += e;   // col partials (sum over mi)
        }
    float cv[4];
#pragma unroll
    for (int ni = 0; ni < 4; ++ni)
        cv[ni] = (cv4[ni][0] + cv4[ni][1]) + (cv4[ni][2] + cv4[ni][3]);

    // Row butterfly all-reduce over the 16 lanes of each quad; end: f[0] <-> p = l15.
#pragma unroll
    for (int s = 0; s < 4; ++s) {
        const bool b = (l15 >> s) & 1;
#pragma unroll
        for (int i = 0; i < (8 >> s); ++i) {
            const float a0 = rvu.f[2 * i], a1 = rvu.f[2 * i + 1];
            const float keep = b ? a1 : a0;
            const float send = b ? a0 : a1;
            rvu.f[i] = keep + __shfl_xor(send, 1 << s);
        }
    }
    atomicAdd(&row_sums[rowBase + m0 + (l15 >> 2) * 16 + quad * 4 + (l15 & 3)], rvu.f[0]);

    // Col butterfly all-reduce over the 4 quads; end: cv[0] <-> ni = quad.
#pragma unroll
    for (int s = 0; s < 2; ++s) {
        const bool b = (quad >> s) & 1;
#pragma unroll
        for (int i = 0; i < (2 >> s); ++i) {
            const float a0 = cv[2 * i], a1 = cv[2 * i + 1];
            const float keep = b ? a1 : a0;
            const float send = b ? a0 : a1;
            cv[i] = keep + __shfl_xor(send, 16 << s);
        }
    }
    atomicAdd(&col_sums[colBase + n0 + quad * 16 + l15], cv[0]);
}

// Kernel 3 (parallel): each block reduces 256 rows, atomicAdd into zeroed out[0].
__global__ __launch_bounds__(256) void finalize_kernel(
    const float* __restrict__ rs, const float* __restrict__ cs,
    const float* __restrict__ dg, float* __restrict__ out) {
    const int i = blockIdx.x * 256 + threadIdx.x;
    float s = logf(rs[i]) + logf(cs[i]) - 2.0f * dg[i];
#pragma unroll
    for (int off = 32; off; off >>= 1) s += __shfl_down(s, off);
    __shared__ float buf[4];
    if ((threadIdx.x & 63) == 0) buf[threadIdx.x >> 6] = s;
    __syncthreads();
    if (threadIdx.x == 0) {
        float tot = (buf[0] + buf[1] + buf[2] + buf[3]) / (2.0f * B_ROWS);
        if (blockIdx.x == 0) tot += TEMP_INV;   // undo the fixed exp shift
        atomicAdd(out, tot);
    }
}

extern "C" void kernel_launch(void* const* d_in, const int* in_sizes, int n_in,
                              void* d_out, int out_size, void* d_ws, size_t ws_size,
                              hipStream_t stream) {
    const float* q = (const float*)d_in[0];
    const float* d = (const float*)d_in[1];
    float* out = (float*)d_out;

    char* ws = (char*)d_ws;
    unsigned char* qn = (unsigned char*)ws;                         // 4 MB fp8
    unsigned char* dn = qn + (size_t)B_ROWS * D_DIM;                // 4 MB fp8
    float* row_sums = (float*)(ws + 2 * (size_t)B_ROWS * D_DIM);
    float* col_sums = row_sums + B_ROWS;
    float* diag     = col_sums + B_ROWS;

    norm_diag_kernel<<<B_ROWS / 4, 256, 0, stream>>>(
        q, d, (unsigned int*)qn, (unsigned int*)dn, diag, row_sums, col_sums, out);
    gemm_lse_kernel<<<(B_ROWS / BM) * (B_ROWS / BN), 512, 0, stream>>>(
        qn, dn, row_sums, col_sums);
    finalize_kernel<<<B_ROWS / 256, 256, 0, stream>>>(row_sums, col_sums, diag, out);
}

// Round 15
// 189.188 us; speedup vs baseline: 1.1687x; 1.1687x over previous
//
#include <hip/hip_runtime.h>
#include <hip/hip_bf16.h>
#include <cstdint>
#include <cstddef>

#define B_ROWS 16384
#define D_DIM  256
#define TEMP_INV 14.285714285714286f   // 1/0.07

#define BM 128
#define BN 128
#define BK 128   // fp8 elems per K-tile -> 128 B LDS row stride (proven conflict-free)

using frag_cd = __attribute__((ext_vector_type(4))) float;   // 4 fp32
using i32x4   = __attribute__((ext_vector_type(4))) int;     // one 16B LDS chunk
using i32x8   = __attribute__((ext_vector_type(8))) int;     // 32B f8f6f4 operand

__device__ __forceinline__ void gld_lds16(const void* g, void* l) {
    __builtin_amdgcn_global_load_lds(
        (const __attribute__((address_space(1))) void*)g,
        (__attribute__((address_space(3))) void*)l,
        16, 0, 0);
}

// Kernel 1: L2-normalize q,d rows -> fp8 e4m3 (HW cvt_pk, RNE); diag[i] exact fp32.
// Also zero-initializes row_sums/col_sums/out (replaces memset dispatches).
__global__ __launch_bounds__(256) void norm_diag_kernel(
    const float* __restrict__ q, const float* __restrict__ d,
    unsigned int* __restrict__ qn, unsigned int* __restrict__ dn,
    float* __restrict__ diag,
    float* __restrict__ row_sums, float* __restrict__ col_sums,
    float* __restrict__ out) {
    const int b = blockIdx.x;
    if (b < 64)            row_sums[b * 256 + threadIdx.x] = 0.0f;
    else if (b < 128)      col_sums[(b - 64) * 256 + threadIdx.x] = 0.0f;
    else if (b == 128 && threadIdx.x == 0) out[0] = 0.0f;

    const int row  = b * 4 + (threadIdx.x >> 6);
    const int lane = threadIdx.x & 63;

    const float4 qv = ((const float4*)(q + (size_t)row * D_DIM))[lane];
    const float4 dv = ((const float4*)(d + (size_t)row * D_DIM))[lane];

    float qss = qv.x*qv.x + qv.y*qv.y + qv.z*qv.z + qv.w*qv.w;
    float dss = dv.x*dv.x + dv.y*dv.y + dv.z*dv.z + dv.w*dv.w;
    float qd  = qv.x*dv.x + qv.y*dv.y + qv.z*dv.z + qv.w*dv.w;
#pragma unroll
    for (int off = 32; off; off >>= 1) {
        qss += __shfl_down(qss, off);
        dss += __shfl_down(dss, off);
        qd  += __shfl_down(qd,  off);
    }
    qss = __shfl(qss, 0);
    dss = __shfl(dss, 0);
    qd  = __shfl(qd,  0);

    const float qinv = 1.0f / fmaxf(sqrtf(qss), 1e-12f);
    const float dinv = 1.0f / fmaxf(sqrtf(dss), 1e-12f);

    // Pack 4 normalized values -> 4 fp8 e4m3 bytes (OCP, HW round-nearest-even).
    int qp = 0, dp = 0;
    qp = __builtin_amdgcn_cvt_pk_fp8_f32(qv.x * qinv, qv.y * qinv, qp, false);
    qp = __builtin_amdgcn_cvt_pk_fp8_f32(qv.z * qinv, qv.w * qinv, qp, true);
    dp = __builtin_amdgcn_cvt_pk_fp8_f32(dv.x * dinv, dv.y * dinv, dp, false);
    dp = __builtin_amdgcn_cvt_pk_fp8_f32(dv.z * dinv, dv.w * dinv, dp, true);
    qn[row * (D_DIM / 4) + lane] = (unsigned int)qp;
    dn[row * (D_DIM / 4) + lane] = (unsigned int)dp;

    if (lane == 0) diag[row] = qd * qinv * dinv * TEMP_INV;
}

// Kernel 2: 128x128 tile of sim = qn . dn^T in fp8 e4m3; fused exp(sim - 1/T) sums.
// R13 skeleton (BK=128 fp8, 128B rows, 16B-chunk XOR swizzle, 2-stage K-loop /
// 3 barriers, XCD grid swizzle, mfma_scale 16x16x128 at unit scales, quad owns
// chunks {q,q+4} -> ds_read_b128 at PC=q^(l15&7) and PC^4 — measured 0 conflicts;
// exp2+packed-f32 epilogue; butterfly all-to-all reduce).
// R15: REGISTER-PRESSURE RESTRUCTURE. R14 post-mortem: occupancy is capped by
// VGPR+AGPR=136 -> 3 waves/SIMD. Keep all 4 B operands resident (32 regs) but
// STREAM A one fragment at a time (8 live) -> peak live regs ~112 -> 4 waves/SIMD
// -> 4 blocks/CU. Attacks the measured no-overlap condition (cycles ~ sum of
// VALU+LDS+MFMA pipes) with +33% wave-TLP.
__global__ __launch_bounds__(256) void gemm_lse_kernel(
    const unsigned char* __restrict__ qn, const unsigned char* __restrict__ dn,
    float* __restrict__ row_sums, float* __restrict__ col_sums) {
    __shared__ unsigned char As[BM][BK];   // 16 KB
    __shared__ unsigned char Bs[BN][BK];   // 16 KB

    const int t    = threadIdx.x;
    const int lane = t & 63;
    const int w    = t >> 6;
    const int l15  = lane & 15;
    const int quad = lane >> 4;
    const int m0   = (w >> 1) * 64;
    const int n0   = (w & 1) * 64;

    // XCD swizzle: id -> (bx, by)
    const int id  = blockIdx.x;
    const int xcd = id & 7;
    const int j   = id >> 3;
    const int bx  = (xcd << 4) | (j & 15);
    const int by  = j >> 4;
    const int rowBase = by * BM;
    const int colBase = bx * BN;

    // staging: thread t -> row t/8 (+32/issue), phys 16B chunk p=t&7,
    // GLOBAL logical chunk g = p^(row&7); LDS offset = t*16.
    const int rsub = t >> 3;
    const int g    = ((t & 7) ^ (rsub & 7)) << 4;   // byte offset of logical chunk
    const unsigned char* ga = qn + (size_t)(rowBase + rsub) * D_DIM + g;
    const unsigned char* gb = dn + (size_t)(colBase + rsub) * D_DIM + g;
    unsigned char* la = &As[0][0] + t * 16;
    unsigned char* lb = &Bs[0][0] + t * 16;

    frag_cd acc[4][4];
#pragma unroll
    for (int i = 0; i < 4; ++i)
#pragma unroll
        for (int jj = 0; jj < 4; ++jj)
            acc[i][jj] = (frag_cd){0.0f, 0.0f, 0.0f, 0.0f};

    // quad's two swizzled chunks (logical pair {q, q+4}): PCa and PCa^4.
    const int PCa = quad ^ (l15 & 7);

    union OpU { i32x8 v; i32x4 h[2]; };

    for (int kt = 0; kt < D_DIM; kt += BK) {
        if (kt) __syncthreads();
#pragma unroll
        for (int it = 0; it < 4; ++it) {   // +32 rows/issue: row&7 invariant
            gld_lds16(ga + (size_t)it * 32 * D_DIM + kt, la + it * 32 * BK);
            gld_lds16(gb + (size_t)it * 32 * D_DIM + kt, lb + it * 32 * BK);
        }
        __syncthreads();   // drains vmcnt (gld_lds) + orders LDS

        // All 4 B operands resident; A streamed one frag at a time (low reg peak).
        OpU b8[4];
#pragma unroll
        for (int i = 0; i < 4; ++i) {
            const unsigned char* rB = &Bs[n0 + i * 16 + l15][0];
            b8[i].h[0] = *(const i32x4*)(rB + PCa * 16);
            b8[i].h[1] = *(const i32x4*)(rB + (PCa ^ 4) * 16);
        }
#pragma unroll
        for (int mi = 0; mi < 4; ++mi) {
            OpU a8;
            const unsigned char* rA = &As[m0 + mi * 16 + l15][0];
            a8.h[0] = *(const i32x4*)(rA + PCa * 16);
            a8.h[1] = *(const i32x4*)(rA + (PCa ^ 4) * 16);
#pragma unroll
            for (int ni = 0; ni < 4; ++ni)
                acc[mi][ni] = __builtin_amdgcn_mfma_scale_f32_16x16x128_f8f6f4(
                    a8.v, b8[ni].v, acc[mi][ni],
                    0, 0,                      // cbsz=FP8 e4m3, blgp=FP8 e4m3
                    0, 0x7F7F7F7F,             // opsel_a, scale_a = 1.0 per block
                    0, 0x7F7F7F7F);            // opsel_b, scale_b = 1.0 per block
        }
    }

    // ---- Epilogue ----
    // C frag layout (shape-determined — m89/m127/m128):
    // lane holds col = n0+ni*16+l15, row = m0+mi*16+quad*4+r.
    // e = exp(sim - 1/T) = 2^(acc*C - C), C = (1/T)*log2(e). Packed float4 math.
    const float C2 = TEMP_INV * 1.44269504088896f;
    union { frag_cd v[4]; float f[16]; } rvu;
    frag_cd cv4[4];
#pragma unroll
    for (int i = 0; i < 4; ++i) {
        rvu.v[i] = (frag_cd){0.0f, 0.0f, 0.0f, 0.0f};
        cv4[i]   = (frag_cd){0.0f, 0.0f, 0.0f, 0.0f};
    }
#pragma unroll
    for (int mi = 0; mi < 4; ++mi)
#pragma unroll
        for (int ni = 0; ni < 4; ++ni) {
            const frag_cd tt = acc[mi][ni] * C2 - C2;   // v_pk_fma_f32 x2
            frag_cd e;
#pragma unroll
            for (int r = 0; r < 4; ++r) e[r] = __builtin_amdgcn_exp2f(tt[r]);
            rvu.v[mi] += e;   // row partials (sum over ni)
            cv4[ni]   += e;   // col partials (sum over mi)
        }
    float cv[4];
#pragma unroll
    for (int ni = 0; ni < 4; ++ni)
        cv[ni] = (cv4[ni][0] + cv4[ni][1]) + (cv4[ni][2] + cv4[ni][3]);

    // Row butterfly all-reduce over the 16 lanes of each quad; end: f[0] <-> p = l15.
#pragma unroll
    for (int s = 0; s < 4; ++s) {
        const bool b = (l15 >> s) & 1;
#pragma unroll
        for (int i = 0; i < (8 >> s); ++i) {
            const float a0 = rvu.f[2 * i], a1 = rvu.f[2 * i + 1];
            const float keep = b ? a1 : a0;
            const float send = b ? a0 : a1;
            rvu.f[i] = keep + __shfl_xor(send, 1 << s);
        }
    }
    atomicAdd(&row_sums[rowBase + m0 + (l15 >> 2) * 16 + quad * 4 + (l15 & 3)], rvu.f[0]);

    // Col butterfly all-reduce over the 4 quads; end: cv[0] <-> ni = quad.
#pragma unroll
    for (int s = 0; s < 2; ++s) {
        const bool b = (quad >> s) & 1;
#pragma unroll
        for (int i = 0; i < (2 >> s); ++i) {
            const float a0 = cv[2 * i], a1 = cv[2 * i + 1];
            const float keep = b ? a1 : a0;
            const float send = b ? a0 : a1;
            cv[i] = keep + __shfl_xor(send, 16 << s);
        }
    }
    atomicAdd(&col_sums[colBase + n0 + quad * 16 + l15], cv[0]);
}

// Kernel 3 (parallel): each block reduces 256 rows, atomicAdd into zeroed out[0].
__global__ __launch_bounds__(256) void finalize_kernel(
    const float* __restrict__ rs, const float* __restrict__ cs,
    const float* __restrict__ dg, float* __restrict__ out) {
    const int i = blockIdx.x * 256 + threadIdx.x;
    float s = logf(rs[i]) + logf(cs[i]) - 2.0f * dg[i];
#pragma unroll
    for (int off = 32; off; off >>= 1) s += __shfl_down(s, off);
    __shared__ float buf[4];
    if ((threadIdx.x & 63) == 0) buf[threadIdx.x >> 6] = s;
    __syncthreads();
    if (threadIdx.x == 0) {
        float tot = (buf[0] + buf[1] + buf[2] + buf[3]) / (2.0f * B_ROWS);
        if (blockIdx.x == 0) tot += TEMP_INV;   // undo the fixed exp shift
        atomicAdd(out, tot);
    }
}

extern "C" void kernel_launch(void* const* d_in, const int* in_sizes, int n_in,
                              void* d_out, int out_size, void* d_ws, size_t ws_size,
                              hipStream_t stream) {
    const float* q = (const float*)d_in[0];
    const float* d = (const float*)d_in[1];
    float* out = (float*)d_out;

    char* ws = (char*)d_ws;
    unsigned char* qn = (unsigned char*)ws;                         // 4 MB fp8
    unsigned char* dn = qn + (size_t)B_ROWS * D_DIM;                // 4 MB fp8
    float* row_sums = (float*)(ws + 2 * (size_t)B_ROWS * D_DIM);
    float* col_sums = row_sums + B_ROWS;
    float* diag     = col_sums + B_ROWS;

    norm_diag_kernel<<<B_ROWS / 4, 256, 0, stream>>>(
        q, d, (unsigned int*)qn, (unsigned int*)dn, diag, row_sums, col_sums, out);
    gemm_lse_kernel<<<(B_ROWS / BM) * (B_ROWS / BN), 256, 0, stream>>>(
        qn, dn, row_sums, col_sums);
    finalize_kernel<<<B_ROWS / 256, 256, 0, stream>>>(row_sums, col_sums, diag, out);
}

// Round 16
// 182.235 us; speedup vs baseline: 1.2133x; 1.0382x over previous
//
#include <hip/hip_runtime.h>
#include <hip/hip_bf16.h>
#include <cstdint>
#include <cstddef>

#define B_ROWS 16384
#define D_DIM  256
#define TEMP_INV 14.285714285714286f   // 1/0.07

#define BM 128
#define BN 128
#define BK 128   // fp8 elems per K-tile -> 128 B LDS row stride (proven conflict-free)

using frag_cd = __attribute__((ext_vector_type(4))) float;   // 4 fp32
using i32x4   = __attribute__((ext_vector_type(4))) int;     // one 16B LDS chunk
using i32x8   = __attribute__((ext_vector_type(8))) int;     // 32B f8f6f4 operand

__device__ __forceinline__ void gld_lds16(const void* g, void* l) {
    __builtin_amdgcn_global_load_lds(
        (const __attribute__((address_space(1))) void*)g,
        (__attribute__((address_space(3))) void*)l,
        16, 0, 0);
}

// Kernel 1: L2-normalize q,d rows -> fp8 e4m3 (HW cvt_pk, RNE); diag[i] exact fp32.
// Also zero-initializes row_sums/col_sums/out (replaces memset dispatches).
__global__ __launch_bounds__(256) void norm_diag_kernel(
    const float* __restrict__ q, const float* __restrict__ d,
    unsigned int* __restrict__ qn, unsigned int* __restrict__ dn,
    float* __restrict__ diag,
    float* __restrict__ row_sums, float* __restrict__ col_sums,
    float* __restrict__ out) {
    const int b = blockIdx.x;
    if (b < 64)            row_sums[b * 256 + threadIdx.x] = 0.0f;
    else if (b < 128)      col_sums[(b - 64) * 256 + threadIdx.x] = 0.0f;
    else if (b == 128 && threadIdx.x == 0) out[0] = 0.0f;

    const int row  = b * 4 + (threadIdx.x >> 6);
    const int lane = threadIdx.x & 63;

    const float4 qv = ((const float4*)(q + (size_t)row * D_DIM))[lane];
    const float4 dv = ((const float4*)(d + (size_t)row * D_DIM))[lane];

    float qss = qv.x*qv.x + qv.y*qv.y + qv.z*qv.z + qv.w*qv.w;
    float dss = dv.x*dv.x + dv.y*dv.y + dv.z*dv.z + dv.w*dv.w;
    float qd  = qv.x*dv.x + qv.y*dv.y + qv.z*dv.z + qv.w*dv.w;
#pragma unroll
    for (int off = 32; off; off >>= 1) {
        qss += __shfl_down(qss, off);
        dss += __shfl_down(dss, off);
        qd  += __shfl_down(qd,  off);
    }
    qss = __shfl(qss, 0);
    dss = __shfl(dss, 0);
    qd  = __shfl(qd,  0);

    const float qinv = 1.0f / fmaxf(sqrtf(qss), 1e-12f);
    const float dinv = 1.0f / fmaxf(sqrtf(dss), 1e-12f);

    // Pack 4 normalized values -> 4 fp8 e4m3 bytes (OCP, HW round-nearest-even).
    int qp = 0, dp = 0;
    qp = __builtin_amdgcn_cvt_pk_fp8_f32(qv.x * qinv, qv.y * qinv, qp, false);
    qp = __builtin_amdgcn_cvt_pk_fp8_f32(qv.z * qinv, qv.w * qinv, qp, true);
    dp = __builtin_amdgcn_cvt_pk_fp8_f32(dv.x * dinv, dv.y * dinv, dp, false);
    dp = __builtin_amdgcn_cvt_pk_fp8_f32(dv.z * dinv, dv.w * dinv, dp, true);
    qn[row * (D_DIM / 4) + lane] = (unsigned int)qp;
    dn[row * (D_DIM / 4) + lane] = (unsigned int)dp;

    if (lane == 0) diag[row] = qd * qinv * dinv * TEMP_INV;
}

// Kernel 2: 128x128 tile of sim = qn . dn^T in fp8 e4m3; fused exp(sim - 1/T) sums.
// R15 skeleton (BK=128 fp8, 128B rows, 16B-chunk XOR swizzle, 2-stage K-loop /
// 3 barriers, XCD grid swizzle, mfma_scale 16x16x128 at unit scales, quad owns
// chunks {q,q+4} -> ds_read_b128 at PC=q^(l15&7) and PC^4 — measured 0 conflicts;
// B resident / A streamed; exp2+packed-f32 epilogue; butterfly all-to-all reduce).
// R16: __launch_bounds__(256, 4) — 2nd arg = min 4 waves/EU, capping the unified
// VGPR+AGPR allocation at 128 regs/lane. R14/R15 showed occupancy pinned at
// 3 waves/SIMD by the 136-reg allocation; measured gemm cycles ≈ SUM of
// VALU+LDS+MFMA pipes (no overlap), so the 4th wave/SIMD is the remaining lever.
// Peak live estimate: acc 64 + b8 32 + a8 8 + addressing ~15 ≈ 120 < 128.
__global__ __launch_bounds__(256, 4) void gemm_lse_kernel(
    const unsigned char* __restrict__ qn, const unsigned char* __restrict__ dn,
    float* __restrict__ row_sums, float* __restrict__ col_sums) {
    __shared__ unsigned char As[BM][BK];   // 16 KB
    __shared__ unsigned char Bs[BN][BK];   // 16 KB

    const int t    = threadIdx.x;
    const int lane = t & 63;
    const int w    = t >> 6;
    const int l15  = lane & 15;
    const int quad = lane >> 4;
    const int m0   = (w >> 1) * 64;
    const int n0   = (w & 1) * 64;

    // XCD swizzle: id -> (bx, by)
    const int id  = blockIdx.x;
    const int xcd = id & 7;
    const int j   = id >> 3;
    const int bx  = (xcd << 4) | (j & 15);
    const int by  = j >> 4;
    const int rowBase = by * BM;
    const int colBase = bx * BN;

    // staging: thread t -> row t/8 (+32/issue), phys 16B chunk p=t&7,
    // GLOBAL logical chunk g = p^(row&7); LDS offset = t*16.
    const int rsub = t >> 3;
    const int g    = ((t & 7) ^ (rsub & 7)) << 4;   // byte offset of logical chunk
    const unsigned char* ga = qn + (size_t)(rowBase + rsub) * D_DIM + g;
    const unsigned char* gb = dn + (size_t)(colBase + rsub) * D_DIM + g;
    unsigned char* la = &As[0][0] + t * 16;
    unsigned char* lb = &Bs[0][0] + t * 16;

    frag_cd acc[4][4];
#pragma unroll
    for (int i = 0; i < 4; ++i)
#pragma unroll
        for (int jj = 0; jj < 4; ++jj)
            acc[i][jj] = (frag_cd){0.0f, 0.0f, 0.0f, 0.0f};

    // quad's two swizzled chunks (logical pair {q, q+4}): PCa and PCa^4.
    const int PCa = quad ^ (l15 & 7);

    union OpU { i32x8 v; i32x4 h[2]; };

    for (int kt = 0; kt < D_DIM; kt += BK) {
        if (kt) __syncthreads();
#pragma unroll
        for (int it = 0; it < 4; ++it) {   // +32 rows/issue: row&7 invariant
            gld_lds16(ga + (size_t)it * 32 * D_DIM + kt, la + it * 32 * BK);
            gld_lds16(gb + (size_t)it * 32 * D_DIM + kt, lb + it * 32 * BK);
        }
        __syncthreads();   // drains vmcnt (gld_lds) + orders LDS

        // All 4 B operands resident; A streamed one frag at a time (low reg peak).
        OpU b8[4];
#pragma unroll
        for (int i = 0; i < 4; ++i) {
            const unsigned char* rB = &Bs[n0 + i * 16 + l15][0];
            b8[i].h[0] = *(const i32x4*)(rB + PCa * 16);
            b8[i].h[1] = *(const i32x4*)(rB + (PCa ^ 4) * 16);
        }
#pragma unroll
        for (int mi = 0; mi < 4; ++mi) {
            OpU a8;
            const unsigned char* rA = &As[m0 + mi * 16 + l15][0];
            a8.h[0] = *(const i32x4*)(rA + PCa * 16);
            a8.h[1] = *(const i32x4*)(rA + (PCa ^ 4) * 16);
#pragma unroll
            for (int ni = 0; ni < 4; ++ni)
                acc[mi][ni] = __builtin_amdgcn_mfma_scale_f32_16x16x128_f8f6f4(
                    a8.v, b8[ni].v, acc[mi][ni],
                    0, 0,                      // cbsz=FP8 e4m3, blgp=FP8 e4m3
                    0, 0x7F7F7F7F,             // opsel_a, scale_a = 1.0 per block
                    0, 0x7F7F7F7F);            // opsel_b, scale_b = 1.0 per block
        }
    }

    // ---- Epilogue ----
    // C frag layout (shape-determined — m89/m127/m128):
    // lane holds col = n0+ni*16+l15, row = m0+mi*16+quad*4+r.
    // e = exp(sim - 1/T) = 2^(acc*C - C), C = (1/T)*log2(e). Packed float4 math.
    const float C2 = TEMP_INV * 1.44269504088896f;
    union { frag_cd v[4]; float f[16]; } rvu;
    frag_cd cv4[4];
#pragma unroll
    for (int i = 0; i < 4; ++i) {
        rvu.v[i] = (frag_cd){0.0f, 0.0f, 0.0f, 0.0f};
        cv4[i]   = (frag_cd){0.0f, 0.0f, 0.0f, 0.0f};
    }
#pragma unroll
    for (int mi = 0; mi < 4; ++mi)
#pragma unroll
        for (int ni = 0; ni < 4; ++ni) {
            const frag_cd tt = acc[mi][ni] * C2 - C2;   // v_pk_fma_f32 x2
            frag_cd e;
#pragma unroll
            for (int r = 0; r < 4; ++r) e[r] = __builtin_amdgcn_exp2f(tt[r]);
            rvu.v[mi] += e;   // row partials (sum over ni)
            cv4[ni]   += e;   // col partials (sum over mi)
        }
    float cv[4];
#pragma unroll
    for (int ni = 0; ni < 4; ++ni)
        cv[ni] = (cv4[ni][0] + cv4[ni][1]) + (cv4[ni][2] + cv4[ni][3]);

    // Row butterfly all-reduce over the 16 lanes of each quad; end: f[0] <-> p = l15.
#pragma unroll
    for (int s = 0; s < 4; ++s) {
        const bool b = (l15 >> s) & 1;
#pragma unroll
        for (int i = 0; i < (8 >> s); ++i) {
            const float a0 = rvu.f[2 * i], a1 = rvu.f[2 * i + 1];
            const float keep = b ? a1 : a0;
            const float send = b ? a0 : a1;
            rvu.f[i] = keep + __shfl_xor(send, 1 << s);
        }
    }
    atomicAdd(&row_sums[rowBase + m0 + (l15 >> 2) * 16 + quad * 4 + (l15 & 3)], rvu.f[0]);

    // Col butterfly all-reduce over the 4 quads; end: cv[0] <-> ni = quad.
#pragma unroll
    for (int s = 0; s < 2; ++s) {
        const bool b = (quad >> s) & 1;
#pragma unroll
        for (int i = 0; i < (2 >> s); ++i) {
            const float a0 = cv[2 * i], a1 = cv[2 * i + 1];
            const float keep = b ? a1 : a0;
            const float send = b ? a0 : a1;
            cv[i] = keep + __shfl_xor(send, 16 << s);
        }
    }
    atomicAdd(&col_sums[colBase + n0 + quad * 16 + l15], cv[0]);
}

// Kernel 3 (parallel): each block reduces 256 rows, atomicAdd into zeroed out[0].
__global__ __launch_bounds__(256) void finalize_kernel(
    const float* __restrict__ rs, const float* __restrict__ cs,
    const float* __restrict__ dg, float* __restrict__ out) {
    const int i = blockIdx.x * 256 + threadIdx.x;
    float s = logf(rs[i]) + logf(cs[i]) - 2.0f * dg[i];
#pragma unroll
    for (int off = 32; off; off >>= 1) s += __shfl_down(s, off);
    __shared__ float buf[4];
    if ((threadIdx.x & 63) == 0) buf[threadIdx.x >> 6] = s;
    __syncthreads();
    if (threadIdx.x == 0) {
        float tot = (buf[0] + buf[1] + buf[2] + buf[3]) / (2.0f * B_ROWS);
        if (blockIdx.x == 0) tot += TEMP_INV;   // undo the fixed exp shift
        atomicAdd(out, tot);
    }
}

extern "C" void kernel_launch(void* const* d_in, const int* in_sizes, int n_in,
                              void* d_out, int out_size, void* d_ws, size_t ws_size,
                              hipStream_t stream) {
    const float* q = (const float*)d_in[0];
    const float* d = (const float*)d_in[1];
    float* out = (float*)d_out;

    char* ws = (char*)d_ws;
    unsigned char* qn = (unsigned char*)ws;                         // 4 MB fp8
    unsigned char* dn = qn + (size_t)B_ROWS * D_DIM;                // 4 MB fp8
    float* row_sums = (float*)(ws + 2 * (size_t)B_ROWS * D_DIM);
    float* col_sums = row_sums + B_ROWS;
    float* diag     = col_sums + B_ROWS;

    norm_diag_kernel<<<B_ROWS / 4, 256, 0, stream>>>(
        q, d, (unsigned int*)qn, (unsigned int*)dn, diag, row_sums, col_sums, out);
    gemm_lse_kernel<<<(B_ROWS / BM) * (B_ROWS / BN), 256, 0, stream>>>(
        qn, dn, row_sums, col_sums);
    finalize_kernel<<<B_ROWS / 256, 256, 0, stream>>>(row_sums, col_sums, diag, out);
}